// Round 1
// 526.922 us; speedup vs baseline: 1.1076x; 1.1076x over previous
//
#include <hip/hip_runtime.h>
#include <hip/hip_bf16.h>
#include <cstddef>
#include <cstdint>

typedef __bf16 bf16;
typedef __bf16 bf16x4 __attribute__((ext_vector_type(4)));
typedef __bf16 bf16x8 __attribute__((ext_vector_type(8)));
typedef float f32x4 __attribute__((ext_vector_type(4)));
typedef float f32x16 __attribute__((ext_vector_type(16)));
typedef unsigned int u32x4 __attribute__((ext_vector_type(4)));

#define GLD_LDS16(g, l) __builtin_amdgcn_global_load_lds( \
    (const __attribute__((address_space(1))) void*)(g),   \
    (__attribute__((address_space(3))) void*)(l), 16, 0, 0)

// pack two f32 -> one u32 of 2 bf16 (elem0 = lo, elem1 = hi)
static __device__ inline unsigned int cvtpk(float lo, float hi) {
  unsigned int r;
  asm("v_cvt_pk_bf16_f32 %0, %1, %2" : "=v"(r) : "v"(lo), "v"(hi));
  return r;
}
// v_permlane32_swap_b32: a.hi32lanes <-> b.lo32lanes
// post: a = [a.lo | b.lo], b = [a.hi | b.hi]
static __device__ inline void plswap(unsigned int& a, unsigned int& b) {
  asm("v_permlane32_swap_b32 %0, %1" : "+v"(a), "+v"(b));
}

// ---------------- src cast: f32 -> bf16, 8 elems/thread ----------------
__global__ void __launch_bounds__(256)
k_cast(const float* __restrict__ in, bf16* __restrict__ out) {
  int gid = blockIdx.x * 256 + threadIdx.x;
  f32x4 a = ((const f32x4*)in)[gid * 2];
  f32x4 b = ((const f32x4*)in)[gid * 2 + 1];
  bf16x8 o;
#pragma unroll
  for (int i = 0; i < 4; ++i) { o[i] = (bf16)a[i]; o[i + 4] = (bf16)b[i]; }
  ((bf16x8*)out)[gid] = o;
}

// ---- tiled transpose: in f32 (R x C) -> out bf16 (C x R), 64x64 tiles ----
__global__ void __launch_bounds__(256)
k_transpose_t(const float* __restrict__ in, bf16* __restrict__ out, int R, int C) {
  __shared__ float tile[64][68];
  const int nct = C >> 6;
  const int bc = blockIdx.x % nct, br = blockIdx.x / nct;
  const int r0 = br << 6, c0 = bc << 6;
  const int t = threadIdx.x;
  const int tr = t >> 4, tc4 = (t & 15) << 2;
#pragma unroll
  for (int i = 0; i < 4; ++i)
    *(f32x4*)&tile[i * 16 + tr][tc4] =
        *(const f32x4*)&in[(size_t)(r0 + i * 16 + tr) * C + c0 + tc4];
  __syncthreads();
  const int c = t >> 2, rch = (t & 3) << 4;
  bf16 ob[16];
#pragma unroll
  for (int j = 0; j < 16; ++j) ob[j] = (bf16)tile[rch + j][c];
  bf16* dst = out + (size_t)(c0 + c) * R + r0 + rch;
  *(bf16x8*)&dst[0] = *(bf16x8*)&ob[0];
  *(bf16x8*)&dst[8] = *(bf16x8*)&ob[8];
}

// ---- QKV weight repack (tiled): W (H,D,DK) f32 -> WqkvT[(proj*1024+h*64+dk)][d] bf16 ----
__global__ void __launch_bounds__(256)
k_reorder_qkv_t(const float* __restrict__ Wq, const float* __restrict__ Wk,
                const float* __restrict__ Wv, bf16* __restrict__ WqkvT) {
  __shared__ float tile[64][68];
  const int bid = blockIdx.x;
  const int sub = bid >> 4, tl = bid & 15;
  const int proj = sub >> 4, h = sub & 15;
  const float* W = (proj == 0) ? Wq : (proj == 1) ? Wk : Wv;
  const float* src = W + (size_t)h * 65536;   // (1024 d x 64 dk)
  const int r0 = tl << 6;
  const int t = threadIdx.x, tr = t >> 4, tc4 = (t & 15) << 2;
#pragma unroll
  for (int i = 0; i < 4; ++i)
    *(f32x4*)&tile[i * 16 + tr][tc4] =
        *(const f32x4*)&src[(size_t)(r0 + i * 16 + tr) * 64 + tc4];
  __syncthreads();
  const int c = t >> 2, rch = (t & 3) << 4;   // c = dk
  bf16 ob[16];
#pragma unroll
  for (int j = 0; j < 16; ++j) ob[j] = (bf16)tile[rch + j][c];
  bf16* dst = WqkvT + ((size_t)(proj * 1024 + h * 64 + c)) * 1024 + r0 + rch;
  *(bf16x8*)&dst[0] = *(bf16x8*)&ob[0];
  *(bf16x8*)&dst[8] = *(bf16x8*)&ob[8];
}

__global__ void __launch_bounds__(256)
k_bias_qkv(const float* __restrict__ bq, const float* __restrict__ bk,
           const float* __restrict__ bv, float* __restrict__ bqkv) {
  int n = blockIdx.x * 256 + threadIdx.x;   // 3072
  int proj = n >> 10, wi = n & 1023;
  const float* bb = (proj == 0) ? bq : (proj == 1) ? bk : bv;
  bqkv[n] = bb[wi];
}

// ---------------- GEMM: C = A(MxK) @ Bt(NxK)^T + bias, BK=64 split-plane ----------------
// MODE 0: scatter QKV (bf16): q(b,h,s,dk) pre-scaled by log2e/8, k(b,h,s,dk), vT(b,h,dk,s)
// MODE 1: bf16 row-major out
// MODE 2: relu -> bf16 row-major out
template <int MODE>
__global__ void __launch_bounds__(256)
k_gemm_bt(const bf16* __restrict__ A, const bf16* __restrict__ Bt,
          const float* __restrict__ bias, void* __restrict__ outp,
          int M, int N, int K,
          bf16* __restrict__ qb, bf16* __restrict__ kb, bf16* __restrict__ vb) {
  // two K-planes of [128][32] per operand: plane p holds k in [k0+32p, k0+32p+32)
  __shared__ __align__(16) bf16 As[2][128][32];
  __shared__ __align__(16) bf16 Bs[2][128][32];
  const int tid = threadIdx.x;
  const int wave = tid >> 6, lane = tid & 63;
  const int l16 = lane & 15, lq = lane >> 4;
  const int mtiles = M >> 7;
  const int tile_m = (blockIdx.x % mtiles) << 7;
  const int tile_n = (blockIdx.x / mtiles) << 7;
  const int wm = (wave >> 1) << 6, wn = (wave & 1) << 6;

  const bf16* Arow = A + (size_t)tile_m * K;
  const bf16* Brow = Bt + (size_t)tile_n * K;
  bf16* As_f = &As[0][0][0];
  bf16* Bs_f = &Bs[0][0][0];

  int gA[4], rA[4], kA[4];
#pragma unroll
  for (int j = 0; j < 4; ++j) {
    gA[j] = j * 4 + wave;
    rA[j] = (gA[j] & 7) * 16 + (lane >> 2);
    kA[j] = (gA[j] >> 3) * 32 + (lane & 3) * 8;
  }

  f32x4 acc[4][4] = {};

  for (int k0 = 0; k0 < K; k0 += 64) {
    __syncthreads();
#pragma unroll
    for (int j = 0; j < 4; ++j) {
      GLD_LDS16(Arow + (size_t)rA[j] * K + k0 + kA[j], As_f + gA[j] * 512);
      GLD_LDS16(Brow + (size_t)rA[j] * K + k0 + kA[j], Bs_f + gA[j] * 512);
    }
    __syncthreads();
#pragma unroll
    for (int p = 0; p < 2; ++p) {
      bf16x8 af[4], bfr[4];
#pragma unroll
      for (int mi = 0; mi < 4; ++mi)
        af[mi] = *(const bf16x8*)&As[p][wm + mi * 16 + l16][lq * 8];
#pragma unroll
      for (int ni = 0; ni < 4; ++ni)
        bfr[ni] = *(const bf16x8*)&Bs[p][wn + ni * 16 + l16][lq * 8];
#pragma unroll
      for (int mi = 0; mi < 4; ++mi)
#pragma unroll
        for (int ni = 0; ni < 4; ++ni)
          acc[mi][ni] = __builtin_amdgcn_mfma_f32_16x16x32_bf16(af[mi], bfr[ni], acc[mi][ni], 0, 0, 0);
    }
  }

#pragma unroll
  for (int mi = 0; mi < 4; ++mi) {
#pragma unroll
    for (int ni = 0; ni < 4; ++ni) {
      const int gn = tile_n + wn + ni * 16 + l16;
      const float bb = bias[gn];
      f32x4 v = acc[mi][ni];
      const int gm0 = tile_m + wm + mi * 16 + lq * 4;
      if (MODE == 0) {
        int proj = gn >> 10, wi = gn & 1023;
        int h = wi >> 6, dk = wi & 63;
        int b = gm0 >> 11, sdx = gm0 & 2047;
        size_t bhs = (size_t)((b << 4) + h);
        if (proj == 0) {
#pragma unroll
          for (int i = 0; i < 4; ++i)
            qb[(bhs * 2048 + sdx + i) * 64 + dk] = (bf16)((v[i] + bb) * 0.18033688f);
        } else if (proj == 1) {
#pragma unroll
          for (int i = 0; i < 4; ++i)
            kb[(bhs * 2048 + sdx + i) * 64 + dk] = (bf16)(v[i] + bb);
        } else {
          bf16x4 pk;
#pragma unroll
          for (int i = 0; i < 4; ++i) pk[i] = (bf16)(v[i] + bb);
          *(bf16x4*)&vb[(bhs * 64 + dk) * 2048 + sdx] = pk;   // V^T, 8B packed
        }
      } else if (MODE == 1) {
#pragma unroll
        for (int i = 0; i < 4; ++i)
          ((bf16*)outp)[(size_t)(gm0 + i) * N + gn] = (bf16)(v[i] + bb);
      } else {
#pragma unroll
        for (int i = 0; i < 4; ++i)
          ((bf16*)outp)[(size_t)(gm0 + i) * N + gn] = (bf16)fmaxf(v[i] + bb, 0.f);
      }
    }
  }
}

// ---- flash attention, 32x32 MFMA version ----
// block = (b,h, 256 q-rows); 4 waves x 64 q (2 subtiles of 32: A = +0, B = +32).
// KV tile = 64 s, double-buffered in LDS via global_load_lds with XOR-swizzled source.
// Swapped QK^T: S^T = mfma(Kfrag, Qfrag) -> lane owns q-col (l&31); P redistributed
// to PV A-fragments fully in-register via v_cvt_pk_bf16_f32 + v_permlane32_swap_b32.
// Q pre-scaled by log2e/8 -> exp2f, no running max (scores bounded).
__global__ void __launch_bounds__(256, 2)
k_attn(const bf16* __restrict__ qb, const bf16* __restrict__ kb,
       const bf16* __restrict__ vb, bf16* __restrict__ ctx) {
  __shared__ __align__(16) bf16 KsL[2][4096];   // [64 s][64 d], swizzled chunks
  __shared__ __align__(16) bf16 VsL[2][4096];   // [64 d][64 s], swizzled chunks

  // bijective XCD-chunked swizzle: 512 wgs = 8 XCD * 64; each XCD owns 8 full (b,h)
  const int bid = blockIdx.x;
  const int wg = (bid & 7) * 64 + (bid >> 3);
  const int bh = wg >> 3, qt = wg & 7;

  const bf16* Qp  = qb + (size_t)bh * 131072 + (size_t)qt * 16384;
  const bf16* Kbh = kb + (size_t)bh * 131072;
  const bf16* Vbh = vb + (size_t)bh * 131072;

  const int tid = threadIdx.x, wave = tid >> 6, lane = tid & 63;
  const int l31 = lane & 31, hi = lane >> 5;

  // Q fragments (B-operand): lane holds Q[q=l31][d = kd*16 + hi*8 + j]
  bf16x8 qfA[4], qfB[4];
  {
    const bf16* qra = Qp + (size_t)(wave * 64 + l31) * 64 + hi * 8;
    const bf16* qrb = qra + 32 * 64;
#pragma unroll
    for (int kd = 0; kd < 4; ++kd) {
      qfA[kd] = *(const bf16x8*)(qra + kd * 16);
      qfB[kd] = *(const bf16x8*)(qrb + kd * 16);
    }
  }

  // staging: thread covers 16B chunks c and c+256; dest linear, source chunk
  // XOR-permuted within its 128B row (involution: chunk ^= row&7)
  const int c0 = tid, c1 = tid + 256;
  const int sw0 = ((c0 ^ (c0 >> 3)) & 7) * 8, rw0 = c0 >> 3;
  const int sw1 = ((c1 ^ (c1 >> 3)) & 7) * 8, rw1 = c1 >> 3;
  const int kof0 = rw0 * 64 + sw0, kof1 = rw1 * 64 + sw1;
  const int vof0 = rw0 * 2048 + sw0, vof1 = rw1 * 2048 + sw1;

  // swizzled LDS read base (bytes): row l31, chunk-XOR (hi ^ row&7)
  const int xr = (hi << 4) ^ ((l31 & 7) << 4);
  const int rb = l31 * 128 + xr;

  f32x16 oA[2] = {}, oB[2] = {};
  float lA = 0.f, lB = 0.f;

#define STAGE_KV(buf, s0)                                             \
  do {                                                                \
    GLD_LDS16(Kbh + (size_t)(s0) * 64 + kof0, &KsL[buf][c0 * 8]);     \
    GLD_LDS16(Kbh + (size_t)(s0) * 64 + kof1, &KsL[buf][c1 * 8]);     \
    GLD_LDS16(Vbh + (s0) + vof0, &VsL[buf][c0 * 8]);                  \
    GLD_LDS16(Vbh + (s0) + vof1, &VsL[buf][c1 * 8]);                  \
  } while (0)

  STAGE_KV(0, 0);
  __syncthreads();

  for (int kt = 0; kt < 32; ++kt) {
    const int cur = kt & 1;
    if (kt < 31) STAGE_KV(cur ^ 1, (kt + 1) * 64);

    const char* Kc = (const char*)&KsL[cur][0];
    const char* Vc = (const char*)&VsL[cur][0];

    bf16x8 paA[4], paB[4];
#pragma unroll
    for (int st = 0; st < 2; ++st) {
      f32x16 sA = {}, sB = {};
      __builtin_amdgcn_s_setprio(1);
#pragma unroll
      for (int kd = 0; kd < 4; ++kd) {
        bf16x8 a = *(const bf16x8*)(Kc + st * 4096 + (rb ^ (kd << 5)));
        sA = __builtin_amdgcn_mfma_f32_32x32x16_bf16(a, qfA[kd], sA, 0, 0, 0);
        sB = __builtin_amdgcn_mfma_f32_32x32x16_bf16(a, qfB[kd], sB, 0, 0, 0);
      }
      __builtin_amdgcn_s_setprio(0);

      // exp2 + denominator partials (lane's q-col = l31)
      float eA[16], eB[16];
#pragma unroll
      for (int i = 0; i < 16; ++i) {
        eA[i] = exp2f(sA[i]); lA += eA[i];
        eB[i] = exp2f(sB[i]); lB += eB[i];
      }
      // pack quads: qd[g][w] = bf16x2 of s32 = 8g + 4hi + {2w, 2w+1}
      unsigned int qdA[4][2], qdB[4][2];
#pragma unroll
      for (int g = 0; g < 4; ++g)
#pragma unroll
        for (int w = 0; w < 2; ++w) {
          qdA[g][w] = cvtpk(eA[g * 4 + w * 2], eA[g * 4 + w * 2 + 1]);
          qdB[g][w] = cvtpk(eB[g * 4 + w * 2], eB[g * 4 + w * 2 + 1]);
        }
      // hi/lo half-wave exchange -> PV A-fragments: frag(ks=2*st+a2):
      // lane needs P[q=l31][s = 16*a2 + 8*hi + j]
#pragma unroll
      for (int a2 = 0; a2 < 2; ++a2) {
        unsigned int x0 = qdA[2 * a2][0], y0 = qdA[2 * a2 + 1][0];
        unsigned int x1 = qdA[2 * a2][1], y1 = qdA[2 * a2 + 1][1];
        plswap(x0, y0); plswap(x1, y1);
        u32x4 fA = {x0, x1, y0, y1};
        paA[st * 2 + a2] = __builtin_bit_cast(bf16x8, fA);
        unsigned int u0 = qdB[2 * a2][0], v0 = qdB[2 * a2 + 1][0];
        unsigned int u1 = qdB[2 * a2][1], v1 = qdB[2 * a2 + 1][1];
        plswap(u0, v0); plswap(u1, v1);
        u32x4 fB = {u0, u1, v0, v1};
        paB[st * 2 + a2] = __builtin_bit_cast(bf16x8, fB);
      }
    }

    __builtin_amdgcn_s_setprio(1);
#pragma unroll
    for (int nd = 0; nd < 2; ++nd)
#pragma unroll
      for (int ks = 0; ks < 4; ++ks) {
        bf16x8 vf = *(const bf16x8*)(Vc + nd * 4096 + (rb ^ (ks << 5)));
        oA[nd] = __builtin_amdgcn_mfma_f32_32x32x16_bf16(paA[ks], vf, oA[nd], 0, 0, 0);
        oB[nd] = __builtin_amdgcn_mfma_f32_32x32x16_bf16(paB[ks], vf, oB[nd], 0, 0, 0);
      }
    __builtin_amdgcn_s_setprio(0);

    __syncthreads();
  }
#undef STAGE_KV

  // denominators: lane partial covers its hi-half of every s-block for q=l31
  const float ltA = lA + __shfl_xor(lA, 32);
  const float ltB = lB + __shfl_xor(lB, 32);
  const float ivA = 1.f / ltA;
  const float ivB = 1.f / ltB;

  const int b = bh >> 4, h = bh & 15;
  const size_t rowbase = (size_t)(b * 2048 + qt * 256 + wave * 64);
#pragma unroll
  for (int r = 0; r < 16; ++r) {
    const int qr = (r & 3) + 8 * (r >> 2) + 4 * hi;   // C/D row map
    const float dA = __shfl(ivA, qr);
    const float dB = __shfl(ivB, qr);
#pragma unroll
    for (int nd = 0; nd < 2; ++nd) {
      const int dk = nd * 32 + l31;
      ctx[(rowbase + qr) * 1024 + h * 64 + dk]      = (bf16)(oA[nd][r] * dA);
      ctx[(rowbase + 32 + qr) * 1024 + h * 64 + dk] = (bf16)(oB[nd][r] * dB);
    }
  }
}

// ------------- residual + layernorm: out = LN(resid + delta)*g + b -------------
template <typename RT, typename DT, typename OT>
__global__ void __launch_bounds__(256)
k_ln(const RT* __restrict__ resid, const DT* __restrict__ delta,
     const float* __restrict__ g, const float* __restrict__ bta,
     OT* __restrict__ out) {
  const int row = blockIdx.x, tid = threadIdx.x;
  const int wave = tid >> 6, lane = tid & 63;
  __shared__ float rs_[4], rs2_[4];
  const RT* r = resid + (size_t)row * 1024;
  const DT* d = delta + (size_t)row * 1024;
  OT* o = out + (size_t)row * 1024;
  float x[4], s = 0.f, s2 = 0.f;
#pragma unroll
  for (int j = 0; j < 4; ++j) {
    int idx = tid + j * 256;
    float v = (float)r[idx] + (float)d[idx];
    x[j] = v; s += v; s2 += v * v;
  }
#pragma unroll
  for (int m = 32; m >= 1; m >>= 1) { s += __shfl_xor(s, m); s2 += __shfl_xor(s2, m); }
  if (lane == 0) { rs_[wave] = s; rs2_[wave] = s2; }
  __syncthreads();
  float ts = rs_[0] + rs_[1] + rs_[2] + rs_[3];
  float ts2 = rs2_[0] + rs2_[1] + rs2_[2] + rs2_[3];
  float mean = ts * (1.f / 1024.f);
  float var = ts2 * (1.f / 1024.f) - mean * mean;
  float rstd = rsqrtf(var + 1e-5f);
#pragma unroll
  for (int j = 0; j < 4; ++j) {
    int idx = tid + j * 256;
    o[idx] = (OT)((x[j] - mean) * rstd * g[idx] + bta[idx]);
  }
}

// ---------------- launch ----------------
extern "C" void kernel_launch(void* const* d_in, const int* in_sizes, int n_in,
                              void* d_out, int out_size, void* d_ws, size_t ws_size,
                              hipStream_t stream) {
  const float* src  = (const float*)d_in[0];
  const float* Wq   = (const float*)d_in[1];
  const float* bq   = (const float*)d_in[2];
  const float* Wk   = (const float*)d_in[3];
  const float* bk   = (const float*)d_in[4];
  const float* Wv   = (const float*)d_in[5];
  const float* bv   = (const float*)d_in[6];
  const float* Wo   = (const float*)d_in[7];
  const float* bo   = (const float*)d_in[8];
  const float* ln1g = (const float*)d_in[9];
  const float* ln1b = (const float*)d_in[10];
  const float* W1   = (const float*)d_in[11];
  const float* b1   = (const float*)d_in[12];
  const float* W2   = (const float*)d_in[13];
  const float* b2   = (const float*)d_in[14];
  const float* ln2g = (const float*)d_in[15];
  const float* ln2b = (const float*)d_in[16];

  char* p = (char*)d_ws;
  bf16*  WqkvT = (bf16*)p;  p += (size_t)3072 * 1024 * 2;
  float* bqkv  = (float*)p; p += 16384;
  bf16*  WoT   = (bf16*)p;  p += (size_t)1024 * 1024 * 2;
  bf16*  W1T   = (bf16*)p;  p += (size_t)4096 * 1024 * 2;
  bf16*  W2T   = (bf16*)p;  p += (size_t)1024 * 4096 * 2;
  bf16*  srcb  = (bf16*)p;  p += (size_t)8388608 * 2;
  bf16*  qbuf  = (bf16*)p;  p += (size_t)8388608 * 2;
  bf16*  kbuf  = (bf16*)p;  p += (size_t)8388608 * 2;
  bf16*  vbuf  = (bf16*)p;  p += (size_t)8388608 * 2;   // V^T (b,h,dk,s)
  bf16*  ctx   = (bf16*)p;  p += (size_t)8388608 * 2;
  bf16*  x1    = (bf16*)p;  p += (size_t)8388608 * 2;
  bf16*  ff1   = (bf16*)p;  p += (size_t)8192 * 4096 * 2;
  bf16*  tmp   = qbuf;   // bf16 GEMM out; aliases qbuf (dead after attention)

  k_cast<<<4096, 256, 0, stream>>>(src, srcb);
  k_reorder_qkv_t<<<768, 256, 0, stream>>>(Wq, Wk, Wv, WqkvT);
  k_bias_qkv<<<12, 256, 0, stream>>>(bq, bk, bv, bqkv);
  k_transpose_t<<<256, 256, 0, stream>>>(Wo, WoT, 1024, 1024);
  k_transpose_t<<<1024, 256, 0, stream>>>(W1, W1T, 1024, 4096);
  k_transpose_t<<<1024, 256, 0, stream>>>(W2, W2T, 4096, 1024);

  // QKV projection: (8192x1024) @ (1024x3072)
  k_gemm_bt<0><<<64 * 24, 256, 0, stream>>>(srcb, WqkvT, bqkv, nullptr,
                                            8192, 3072, 1024, qbuf, kbuf, vbuf);
  // attention -> ctx (B,S,H*DK)
  k_attn<<<512, 256, 0, stream>>>(qbuf, kbuf, vbuf, ctx);
  // out projection -> tmp (bf16)
  k_gemm_bt<1><<<64 * 8, 256, 0, stream>>>(ctx, WoT, bo, tmp,
                                           8192, 1024, 1024, nullptr, nullptr, nullptr);
  // x1 = LN(src + tmp)
  k_ln<float, bf16, bf16><<<8192, 256, 0, stream>>>(src, tmp, ln1g, ln1b, x1);
  // ff1 = relu(x1 @ W1 + b1)
  k_gemm_bt<2><<<64 * 32, 256, 0, stream>>>(x1, W1T, b1, ff1,
                                            8192, 4096, 1024, nullptr, nullptr, nullptr);
  // tmp = ff1 @ W2 + b2
  k_gemm_bt<1><<<64 * 8, 256, 0, stream>>>(ff1, W2T, b2, tmp,
                                           8192, 1024, 4096, nullptr, nullptr, nullptr);
  // out = LN(x1 + tmp) -> f32
  k_ln<bf16, bf16, float><<<8192, 256, 0, stream>>>(x1, tmp, ln2g, ln2b, (float*)d_out);
}

// Round 2
// 513.923 us; speedup vs baseline: 1.1356x; 1.0253x over previous
//
#include <hip/hip_runtime.h>
#include <hip/hip_bf16.h>
#include <cstddef>
#include <cstdint>

typedef __bf16 bf16;
typedef __bf16 bf16x4 __attribute__((ext_vector_type(4)));
typedef __bf16 bf16x8 __attribute__((ext_vector_type(8)));
typedef float f32x4 __attribute__((ext_vector_type(4)));
typedef float f32x16 __attribute__((ext_vector_type(16)));
typedef unsigned int u32x4 __attribute__((ext_vector_type(4)));

#define GLD_LDS16(g, l) __builtin_amdgcn_global_load_lds( \
    (const __attribute__((address_space(1))) void*)(g),   \
    (__attribute__((address_space(3))) void*)(l), 16, 0, 0)

// pack two f32 -> one u32 of 2 bf16 (elem0 = lo, elem1 = hi)
static __device__ inline unsigned int cvtpk(float lo, float hi) {
  unsigned int r;
  asm("v_cvt_pk_bf16_f32 %0, %1, %2" : "=v"(r) : "v"(lo), "v"(hi));
  return r;
}
// v_permlane32_swap_b32: a.hi32lanes <-> b.lo32lanes
static __device__ inline void plswap(unsigned int& a, unsigned int& b) {
  asm("v_permlane32_swap_b32 %0, %1" : "+v"(a), "+v"(b));
}
// raw hardware exp2 (inputs bounded; no denormal guard needed)
static __device__ inline float fexp2(float x) {
#if __has_builtin(__builtin_amdgcn_exp2f)
  return __builtin_amdgcn_exp2f(x);
#else
  float r; asm("v_exp_f32 %0, %1" : "=v"(r) : "v"(x)); return r;
#endif
}
// pairwise tree sum of 16 floats (depth 4, no serial chain)
static __device__ inline float tsum16(const float* e) {
  float s0 = e[0] + e[1], s1 = e[2] + e[3], s2 = e[4] + e[5], s3 = e[6] + e[7];
  float s4 = e[8] + e[9], s5 = e[10] + e[11], s6 = e[12] + e[13], s7 = e[14] + e[15];
  return ((s0 + s1) + (s2 + s3)) + ((s4 + s5) + (s6 + s7));
}

// ---------------- src cast: f32 -> bf16, 8 elems/thread ----------------
__global__ void __launch_bounds__(256)
k_cast(const float* __restrict__ in, bf16* __restrict__ out) {
  int gid = blockIdx.x * 256 + threadIdx.x;
  f32x4 a = ((const f32x4*)in)[gid * 2];
  f32x4 b = ((const f32x4*)in)[gid * 2 + 1];
  bf16x8 o;
#pragma unroll
  for (int i = 0; i < 4; ++i) { o[i] = (bf16)a[i]; o[i + 4] = (bf16)b[i]; }
  ((bf16x8*)out)[gid] = o;
}

// ---- tiled transpose: in f32 (R x C) -> out bf16 (C x R), 64x64 tiles ----
__global__ void __launch_bounds__(256)
k_transpose_t(const float* __restrict__ in, bf16* __restrict__ out, int R, int C) {
  __shared__ float tile[64][68];
  const int nct = C >> 6;
  const int bc = blockIdx.x % nct, br = blockIdx.x / nct;
  const int r0 = br << 6, c0 = bc << 6;
  const int t = threadIdx.x;
  const int tr = t >> 4, tc4 = (t & 15) << 2;
#pragma unroll
  for (int i = 0; i < 4; ++i)
    *(f32x4*)&tile[i * 16 + tr][tc4] =
        *(const f32x4*)&in[(size_t)(r0 + i * 16 + tr) * C + c0 + tc4];
  __syncthreads();
  const int c = t >> 2, rch = (t & 3) << 4;
  bf16 ob[16];
#pragma unroll
  for (int j = 0; j < 16; ++j) ob[j] = (bf16)tile[rch + j][c];
  bf16* dst = out + (size_t)(c0 + c) * R + r0 + rch;
  *(bf16x8*)&dst[0] = *(bf16x8*)&ob[0];
  *(bf16x8*)&dst[8] = *(bf16x8*)&ob[8];
}

// ---- QKV weight repack (tiled): W (H,D,DK) f32 -> WqkvT[(proj*1024+h*64+dk)][d] bf16 ----
__global__ void __launch_bounds__(256)
k_reorder_qkv_t(const float* __restrict__ Wq, const float* __restrict__ Wk,
                const float* __restrict__ Wv, bf16* __restrict__ WqkvT) {
  __shared__ float tile[64][68];
  const int bid = blockIdx.x;
  const int sub = bid >> 4, tl = bid & 15;
  const int proj = sub >> 4, h = sub & 15;
  const float* W = (proj == 0) ? Wq : (proj == 1) ? Wk : Wv;
  const float* src = W + (size_t)h * 65536;   // (1024 d x 64 dk)
  const int r0 = tl << 6;
  const int t = threadIdx.x, tr = t >> 4, tc4 = (t & 15) << 2;
#pragma unroll
  for (int i = 0; i < 4; ++i)
    *(f32x4*)&tile[i * 16 + tr][tc4] =
        *(const f32x4*)&src[(size_t)(r0 + i * 16 + tr) * 64 + tc4];
  __syncthreads();
  const int c = t >> 2, rch = (t & 3) << 4;   // c = dk
  bf16 ob[16];
#pragma unroll
  for (int j = 0; j < 16; ++j) ob[j] = (bf16)tile[rch + j][c];
  bf16* dst = WqkvT + ((size_t)(proj * 1024 + h * 64 + c)) * 1024 + r0 + rch;
  *(bf16x8*)&dst[0] = *(bf16x8*)&ob[0];
  *(bf16x8*)&dst[8] = *(bf16x8*)&ob[8];
}

__global__ void __launch_bounds__(256)
k_bias_qkv(const float* __restrict__ bq, const float* __restrict__ bk,
           const float* __restrict__ bv, float* __restrict__ bqkv) {
  int n = blockIdx.x * 256 + threadIdx.x;   // 3072
  int proj = n >> 10, wi = n & 1023;
  const float* bb = (proj == 0) ? bq : (proj == 1) ? bk : bv;
  bqkv[n] = bb[wi];
}

// ---------------- GEMM: C = A(MxK) @ Bt(NxK)^T + bias, BK=64 split-plane ----------------
template <int MODE>
__global__ void __launch_bounds__(256)
k_gemm_bt(const bf16* __restrict__ A, const bf16* __restrict__ Bt,
          const float* __restrict__ bias, void* __restrict__ outp,
          int M, int N, int K,
          bf16* __restrict__ qb, bf16* __restrict__ kb, bf16* __restrict__ vb) {
  __shared__ __align__(16) bf16 As[2][128][32];
  __shared__ __align__(16) bf16 Bs[2][128][32];
  const int tid = threadIdx.x;
  const int wave = tid >> 6, lane = tid & 63;
  const int l16 = lane & 15, lq = lane >> 4;
  const int mtiles = M >> 7;
  const int tile_m = (blockIdx.x % mtiles) << 7;
  const int tile_n = (blockIdx.x / mtiles) << 7;
  const int wm = (wave >> 1) << 6, wn = (wave & 1) << 6;

  const bf16* Arow = A + (size_t)tile_m * K;
  const bf16* Brow = Bt + (size_t)tile_n * K;
  bf16* As_f = &As[0][0][0];
  bf16* Bs_f = &Bs[0][0][0];

  int gA[4], rA[4], kA[4];
#pragma unroll
  for (int j = 0; j < 4; ++j) {
    gA[j] = j * 4 + wave;
    rA[j] = (gA[j] & 7) * 16 + (lane >> 2);
    kA[j] = (gA[j] >> 3) * 32 + (lane & 3) * 8;
  }

  f32x4 acc[4][4] = {};

  for (int k0 = 0; k0 < K; k0 += 64) {
    __syncthreads();
#pragma unroll
    for (int j = 0; j < 4; ++j) {
      GLD_LDS16(Arow + (size_t)rA[j] * K + k0 + kA[j], As_f + gA[j] * 512);
      GLD_LDS16(Brow + (size_t)rA[j] * K + k0 + kA[j], Bs_f + gA[j] * 512);
    }
    __syncthreads();
#pragma unroll
    for (int p = 0; p < 2; ++p) {
      bf16x8 af[4], bfr[4];
#pragma unroll
      for (int mi = 0; mi < 4; ++mi)
        af[mi] = *(const bf16x8*)&As[p][wm + mi * 16 + l16][lq * 8];
#pragma unroll
      for (int ni = 0; ni < 4; ++ni)
        bfr[ni] = *(const bf16x8*)&Bs[p][wn + ni * 16 + l16][lq * 8];
#pragma unroll
      for (int mi = 0; mi < 4; ++mi)
#pragma unroll
        for (int ni = 0; ni < 4; ++ni)
          acc[mi][ni] = __builtin_amdgcn_mfma_f32_16x16x32_bf16(af[mi], bfr[ni], acc[mi][ni], 0, 0, 0);
    }
  }

#pragma unroll
  for (int mi = 0; mi < 4; ++mi) {
#pragma unroll
    for (int ni = 0; ni < 4; ++ni) {
      const int gn = tile_n + wn + ni * 16 + l16;
      const float bb = bias[gn];
      f32x4 v = acc[mi][ni];
      const int gm0 = tile_m + wm + mi * 16 + lq * 4;
      if (MODE == 0) {
        int proj = gn >> 10, wi = gn & 1023;
        int h = wi >> 6, dk = wi & 63;
        int b = gm0 >> 11, sdx = gm0 & 2047;
        size_t bhs = (size_t)((b << 4) + h);
        if (proj == 0) {
#pragma unroll
          for (int i = 0; i < 4; ++i)
            qb[(bhs * 2048 + sdx + i) * 64 + dk] = (bf16)((v[i] + bb) * 0.18033688f);
        } else if (proj == 1) {
#pragma unroll
          for (int i = 0; i < 4; ++i)
            kb[(bhs * 2048 + sdx + i) * 64 + dk] = (bf16)(v[i] + bb);
        } else {
          bf16x4 pk;
#pragma unroll
          for (int i = 0; i < 4; ++i) pk[i] = (bf16)(v[i] + bb);
          *(bf16x4*)&vb[(bhs * 64 + dk) * 2048 + sdx] = pk;   // V^T, 8B packed
        }
      } else if (MODE == 1) {
#pragma unroll
        for (int i = 0; i < 4; ++i)
          ((bf16*)outp)[(size_t)(gm0 + i) * N + gn] = (bf16)(v[i] + bb);
      } else {
#pragma unroll
        for (int i = 0; i < 4; ++i)
          ((bf16*)outp)[(size_t)(gm0 + i) * N + gn] = (bf16)fmaxf(v[i] + bb, 0.f);
      }
    }
  }
}

// ---- flash attention, 32x32 MFMA, triple-buffered counted-vmcnt pipeline ----
// block = (b,h, 256 q-rows); 4 waves x 64 q (2 subtiles of 32: A = +0, B = +32).
// KV tile = 64 s; depth-2 prefetch via global_load_lds, raw s_barrier with
// counted s_waitcnt vmcnt(4) (never 0 in main loop). Swapped QK^T; P kept fully
// in-register via v_cvt_pk_bf16_f32 + v_permlane32_swap_b32. Raw v_exp_f32.
__global__ void __launch_bounds__(256, 2)
k_attn(const bf16* __restrict__ qb, const bf16* __restrict__ kb,
       const bf16* __restrict__ vb, bf16* __restrict__ ctx) {
  __shared__ __align__(16) bf16 KsL[3][4096];   // [64 s][64 d], swizzled chunks
  __shared__ __align__(16) bf16 VsL[3][4096];   // [64 d][64 s], swizzled chunks

  // bijective XCD-chunked swizzle: 512 wgs = 8 XCD * 64; each XCD owns 8 full (b,h)
  const int bid = blockIdx.x;
  const int wg = (bid & 7) * 64 + (bid >> 3);
  const int bh = wg >> 3, qt = wg & 7;

  const bf16* Qp  = qb + (size_t)bh * 131072 + (size_t)qt * 16384;
  const bf16* Kbh = kb + (size_t)bh * 131072;
  const bf16* Vbh = vb + (size_t)bh * 131072;

  const int tid = threadIdx.x, wave = tid >> 6, lane = tid & 63;
  const int l31 = lane & 31, hi = lane >> 5;

  // Q fragments (B-operand): lane holds Q[q=l31][d = kd*16 + hi*8 + j]
  bf16x8 qfA[4], qfB[4];
  {
    const bf16* qra = Qp + (size_t)(wave * 64 + l31) * 64 + hi * 8;
    const bf16* qrb = qra + 32 * 64;
#pragma unroll
    for (int kd = 0; kd < 4; ++kd) {
      qfA[kd] = *(const bf16x8*)(qra + kd * 16);
      qfB[kd] = *(const bf16x8*)(qrb + kd * 16);
    }
  }

  // staging: thread covers 16B chunks c and c+256; dest linear, source chunk
  // XOR-permuted within its 128B row (involution: chunk ^= row&7)
  const int c0 = tid, c1 = tid + 256;
  const int sw0 = ((c0 ^ (c0 >> 3)) & 7) * 8, rw0 = c0 >> 3;
  const int sw1 = ((c1 ^ (c1 >> 3)) & 7) * 8, rw1 = c1 >> 3;
  const int kof0 = rw0 * 64 + sw0, kof1 = rw1 * 64 + sw1;
  const int vof0 = rw0 * 2048 + sw0, vof1 = rw1 * 2048 + sw1;

  // swizzled LDS read base (bytes): row l31, chunk-XOR (hi ^ row&7)
  const int xr = (hi << 4) ^ ((l31 & 7) << 4);
  const int rb = l31 * 128 + xr;

  f32x16 oA[2] = {}, oB[2] = {};
  float lA = 0.f, lB = 0.f;

#define STAGE_KV(buf, s0)                                             \
  do {                                                                \
    GLD_LDS16(Kbh + (size_t)(s0) * 64 + kof0, &KsL[buf][c0 * 8]);     \
    GLD_LDS16(Kbh + (size_t)(s0) * 64 + kof1, &KsL[buf][c1 * 8]);     \
    GLD_LDS16(Vbh + (s0) + vof0, &VsL[buf][c0 * 8]);                  \
    GLD_LDS16(Vbh + (s0) + vof1, &VsL[buf][c1 * 8]);                  \
  } while (0)

  STAGE_KV(0, 0);
  STAGE_KV(1, 64);

  int cur = 0;
  for (int kt = 0; kt < 32; ++kt) {
    __builtin_amdgcn_sched_barrier(0);
    if (kt == 31) { asm volatile("s_waitcnt vmcnt(0)" ::: "memory"); }
    else          { asm volatile("s_waitcnt vmcnt(4)" ::: "memory"); }
    __builtin_amdgcn_s_barrier();
    __builtin_amdgcn_sched_barrier(0);

    if (kt < 30) {
      int nx = cur + 2; if (nx >= 3) nx -= 3;
      STAGE_KV(nx, (kt + 2) * 64);
    }

    const char* Kc = (const char*)&KsL[cur][0];
    const char* Vc = (const char*)&VsL[cur][0];

    bf16x8 paA[4], paB[4];
#pragma unroll
    for (int st = 0; st < 2; ++st) {
      f32x16 sA = {}, sB = {};
      __builtin_amdgcn_s_setprio(1);
#pragma unroll
      for (int kd = 0; kd < 4; ++kd) {
        bf16x8 a = *(const bf16x8*)(Kc + st * 4096 + (rb ^ (kd << 5)));
        sA = __builtin_amdgcn_mfma_f32_32x32x16_bf16(a, qfA[kd], sA, 0, 0, 0);
        sB = __builtin_amdgcn_mfma_f32_32x32x16_bf16(a, qfB[kd], sB, 0, 0, 0);
      }
      __builtin_amdgcn_s_setprio(0);

      // exp2 + denominator partials (lane's q-col = l31)
      float eA[16], eB[16];
#pragma unroll
      for (int i = 0; i < 16; ++i) {
        eA[i] = fexp2(sA[i]);
        eB[i] = fexp2(sB[i]);
      }
      lA += tsum16(eA);
      lB += tsum16(eB);
      // pack quads: qd[g][w] = bf16x2 of s32 = 8g + 4hi + {2w, 2w+1}
      unsigned int qdA[4][2], qdB[4][2];
#pragma unroll
      for (int g = 0; g < 4; ++g)
#pragma unroll
        for (int w = 0; w < 2; ++w) {
          qdA[g][w] = cvtpk(eA[g * 4 + w * 2], eA[g * 4 + w * 2 + 1]);
          qdB[g][w] = cvtpk(eB[g * 4 + w * 2], eB[g * 4 + w * 2 + 1]);
        }
      // hi/lo half-wave exchange -> PV A-fragments
#pragma unroll
      for (int a2 = 0; a2 < 2; ++a2) {
        unsigned int x0 = qdA[2 * a2][0], y0 = qdA[2 * a2 + 1][0];
        unsigned int x1 = qdA[2 * a2][1], y1 = qdA[2 * a2 + 1][1];
        plswap(x0, y0); plswap(x1, y1);
        u32x4 fA = {x0, x1, y0, y1};
        paA[st * 2 + a2] = __builtin_bit_cast(bf16x8, fA);
        unsigned int u0 = qdB[2 * a2][0], v0 = qdB[2 * a2 + 1][0];
        unsigned int u1 = qdB[2 * a2][1], v1 = qdB[2 * a2 + 1][1];
        plswap(u0, v0); plswap(u1, v1);
        u32x4 fB = {u0, u1, v0, v1};
        paB[st * 2 + a2] = __builtin_bit_cast(bf16x8, fB);
      }
    }

    __builtin_amdgcn_s_setprio(1);
#pragma unroll
    for (int nd = 0; nd < 2; ++nd)
#pragma unroll
      for (int ks = 0; ks < 4; ++ks) {
        bf16x8 vf = *(const bf16x8*)(Vc + nd * 4096 + (rb ^ (ks << 5)));
        oA[nd] = __builtin_amdgcn_mfma_f32_32x32x16_bf16(paA[ks], vf, oA[nd], 0, 0, 0);
        oB[nd] = __builtin_amdgcn_mfma_f32_32x32x16_bf16(paB[ks], vf, oB[nd], 0, 0, 0);
      }
    __builtin_amdgcn_s_setprio(0);

    if (++cur == 3) cur = 0;
  }
#undef STAGE_KV

  // denominators: lane partial covers its hi-half of every s-block for q=l31
  const float ltA = lA + __shfl_xor(lA, 32);
  const float ltB = lB + __shfl_xor(lB, 32);
  const float ivA = 1.f / ltA;
  const float ivB = 1.f / ltB;

  const int b = bh >> 4, h = bh & 15;
  const size_t rowbase = (size_t)(b * 2048 + qt * 256 + wave * 64);
#pragma unroll
  for (int r = 0; r < 16; ++r) {
    const int qr = (r & 3) + 8 * (r >> 2) + 4 * hi;   // C/D row map
    const float dA = __shfl(ivA, qr);
    const float dB = __shfl(ivB, qr);
#pragma unroll
    for (int nd = 0; nd < 2; ++nd) {
      const int dk = nd * 32 + l31;
      ctx[(rowbase + qr) * 1024 + h * 64 + dk]      = (bf16)(oA[nd][r] * dA);
      ctx[(rowbase + 32 + qr) * 1024 + h * 64 + dk] = (bf16)(oB[nd][r] * dB);
    }
  }
}

// ------------- residual + layernorm: out = LN(resid + delta)*g + b -------------
template <typename RT, typename DT, typename OT>
__global__ void __launch_bounds__(256)
k_ln(const RT* __restrict__ resid, const DT* __restrict__ delta,
     const float* __restrict__ g, const float* __restrict__ bta,
     OT* __restrict__ out) {
  const int row = blockIdx.x, tid = threadIdx.x;
  const int wave = tid >> 6, lane = tid & 63;
  __shared__ float rs_[4], rs2_[4];
  const RT* r = resid + (size_t)row * 1024;
  const DT* d = delta + (size_t)row * 1024;
  OT* o = out + (size_t)row * 1024;
  float x[4], s = 0.f, s2 = 0.f;
#pragma unroll
  for (int j = 0; j < 4; ++j) {
    int idx = tid + j * 256;
    float v = (float)r[idx] + (float)d[idx];
    x[j] = v; s += v; s2 += v * v;
  }
#pragma unroll
  for (int m = 32; m >= 1; m >>= 1) { s += __shfl_xor(s, m); s2 += __shfl_xor(s2, m); }
  if (lane == 0) { rs_[wave] = s; rs2_[wave] = s2; }
  __syncthreads();
  float ts = rs_[0] + rs_[1] + rs_[2] + rs_[3];
  float ts2 = rs2_[0] + rs2_[1] + rs2_[2] + rs2_[3];
  float mean = ts * (1.f / 1024.f);
  float var = ts2 * (1.f / 1024.f) - mean * mean;
  float rstd = rsqrtf(var + 1e-5f);
#pragma unroll
  for (int j = 0; j < 4; ++j) {
    int idx = tid + j * 256;
    o[idx] = (OT)((x[j] - mean) * rstd * g[idx] + bta[idx]);
  }
}

// ---------------- launch ----------------
extern "C" void kernel_launch(void* const* d_in, const int* in_sizes, int n_in,
                              void* d_out, int out_size, void* d_ws, size_t ws_size,
                              hipStream_t stream) {
  const float* src  = (const float*)d_in[0];
  const float* Wq   = (const float*)d_in[1];
  const float* bq   = (const float*)d_in[2];
  const float* Wk   = (const float*)d_in[3];
  const float* bk   = (const float*)d_in[4];
  const float* Wv   = (const float*)d_in[5];
  const float* bv   = (const float*)d_in[6];
  const float* Wo   = (const float*)d_in[7];
  const float* bo   = (const float*)d_in[8];
  const float* ln1g = (const float*)d_in[9];
  const float* ln1b = (const float*)d_in[10];
  const float* W1   = (const float*)d_in[11];
  const float* b1   = (const float*)d_in[12];
  const float* W2   = (const float*)d_in[13];
  const float* b2   = (const float*)d_in[14];
  const float* ln2g = (const float*)d_in[15];
  const float* ln2b = (const float*)d_in[16];

  char* p = (char*)d_ws;
  bf16*  WqkvT = (bf16*)p;  p += (size_t)3072 * 1024 * 2;
  float* bqkv  = (float*)p; p += 16384;
  bf16*  WoT   = (bf16*)p;  p += (size_t)1024 * 1024 * 2;
  bf16*  W1T   = (bf16*)p;  p += (size_t)4096 * 1024 * 2;
  bf16*  W2T   = (bf16*)p;  p += (size_t)1024 * 4096 * 2;
  bf16*  srcb  = (bf16*)p;  p += (size_t)8388608 * 2;
  bf16*  qbuf  = (bf16*)p;  p += (size_t)8388608 * 2;
  bf16*  kbuf  = (bf16*)p;  p += (size_t)8388608 * 2;
  bf16*  vbuf  = (bf16*)p;  p += (size_t)8388608 * 2;   // V^T (b,h,dk,s)
  bf16*  ctx   = (bf16*)p;  p += (size_t)8388608 * 2;
  bf16*  x1    = (bf16*)p;  p += (size_t)8388608 * 2;
  bf16*  ff1   = (bf16*)p;  p += (size_t)8192 * 4096 * 2;
  bf16*  tmp   = qbuf;   // bf16 GEMM out; aliases qbuf (dead after attention)

  k_cast<<<4096, 256, 0, stream>>>(src, srcb);
  k_reorder_qkv_t<<<768, 256, 0, stream>>>(Wq, Wk, Wv, WqkvT);
  k_bias_qkv<<<12, 256, 0, stream>>>(bq, bk, bv, bqkv);
  k_transpose_t<<<256, 256, 0, stream>>>(Wo, WoT, 1024, 1024);
  k_transpose_t<<<1024, 256, 0, stream>>>(W1, W1T, 1024, 4096);
  k_transpose_t<<<1024, 256, 0, stream>>>(W2, W2T, 4096, 1024);

  // QKV projection: (8192x1024) @ (1024x3072)
  k_gemm_bt<0><<<64 * 24, 256, 0, stream>>>(srcb, WqkvT, bqkv, nullptr,
                                            8192, 3072, 1024, qbuf, kbuf, vbuf);
  // attention -> ctx (B,S,H*DK)
  k_attn<<<512, 256, 0, stream>>>(qbuf, kbuf, vbuf, ctx);
  // out projection -> tmp (bf16)
  k_gemm_bt<1><<<64 * 8, 256, 0, stream>>>(ctx, WoT, bo, tmp,
                                           8192, 1024, 1024, nullptr, nullptr, nullptr);
  // x1 = LN(src + tmp)
  k_ln<float, bf16, bf16><<<8192, 256, 0, stream>>>(src, tmp, ln1g, ln1b, x1);
  // ff1 = relu(x1 @ W1 + b1)
  k_gemm_bt<2><<<64 * 32, 256, 0, stream>>>(x1, W1T, b1, ff1,
                                            8192, 4096, 1024, nullptr, nullptr, nullptr);
  // tmp = ff1 @ W2 + b2
  k_gemm_bt<1><<<64 * 8, 256, 0, stream>>>(ff1, W2T, b2, tmp,
                                           8192, 1024, 4096, nullptr, nullptr, nullptr);
  // out = LN(x1 + tmp) -> f32
  k_ln<bf16, bf16, float><<<8192, 256, 0, stream>>>(x1, tmp, ln2g, ln2b, (float*)d_out);
}